// Round 1
// baseline (389.516 us; speedup 1.0000x reference)
//
#include <hip/hip_runtime.h>

#define NNODES 50000
#define NEDGES 800000
#define EP (NEDGES + NNODES)   // 850000 edges incl. self-loops

// ---------------- CSR build ----------------
__global__ __launch_bounds__(256) void zero_kernel(int* p, int n){
  int i = blockIdx.x*256 + threadIdx.x;
  if(i < n) p[i] = 0;
}

__global__ __launch_bounds__(256) void hist_kernel(const int* __restrict__ ei, int* __restrict__ deg){
  int e = blockIdx.x*256 + threadIdx.x;
  if(e >= EP) return;
  int d = (e < NEDGES) ? ei[NEDGES + e] : (e - NEDGES);
  atomicAdd(&deg[d], 1);
}

// chunk=1024 per block (4 elems/thread), exclusive scan in place, block totals -> partials
__global__ __launch_bounds__(256) void scan1_kernel(int* __restrict__ data, int* __restrict__ partials, int n){
  __shared__ int sm[256];
  int t = threadIdx.x;
  int base = blockIdx.x*1024 + t*4;
  int v0 = (base+0 < n) ? data[base+0] : 0;
  int v1 = (base+1 < n) ? data[base+1] : 0;
  int v2 = (base+2 < n) ? data[base+2] : 0;
  int v3 = (base+3 < n) ? data[base+3] : 0;
  int s = v0+v1+v2+v3;
  sm[t] = s;
  __syncthreads();
  int acc = s;
  #pragma unroll
  for(int d = 1; d < 256; d <<= 1){
    int o = (t >= d) ? sm[t-d] : 0;
    __syncthreads();
    acc += o;
    sm[t] = acc;
    __syncthreads();
  }
  int excl = acc - s;
  if(base+0 < n) data[base+0] = excl;
  if(base+1 < n) data[base+1] = excl + v0;
  if(base+2 < n) data[base+2] = excl + v0 + v1;
  if(base+3 < n) data[base+3] = excl + v0 + v1 + v2;
  if(t == 255) partials[blockIdx.x] = acc;
}

__global__ __launch_bounds__(256) void scan2_kernel(int* __restrict__ partials, int nb){
  __shared__ int sm[256];
  int t = threadIdx.x;
  int s = (t < nb) ? partials[t] : 0;
  sm[t] = s;
  __syncthreads();
  int acc = s;
  #pragma unroll
  for(int d = 1; d < 256; d <<= 1){
    int o = (t >= d) ? sm[t-d] : 0;
    __syncthreads();
    acc += o;
    sm[t] = acc;
    __syncthreads();
  }
  if(t < nb) partials[t] = acc - s;
}

__global__ __launch_bounds__(256) void scan3_kernel(int* __restrict__ data, const int* __restrict__ partials,
                                                    int* __restrict__ cursor, int n){
  int off = partials[blockIdx.x];
  for(int j = threadIdx.x; j < 1024; j += 256){
    int i = blockIdx.x*1024 + j;
    if(i < n){ int v = data[i] + off; data[i] = v; cursor[i] = v; }
  }
}

__global__ __launch_bounds__(256) void scatter_kernel(const int* __restrict__ ei, int* __restrict__ cursor,
                                                      int* __restrict__ esrc){
  int e = blockIdx.x*256 + threadIdx.x;
  if(e >= EP) return;
  int s, d;
  if(e < NEDGES){ s = ei[e]; d = ei[NEDGES + e]; }
  else          { s = d = e - NEDGES; }
  int pos = atomicAdd(&cursor[d], 1);
  esrc[pos] = s;
}

// ---------------- GEMM + attention-score epilogue ----------------
// h[n][128] = in[n][0:K] @ W[K][128]; asrc[n][hh] = sum_c h[n][hh*64+c]*att_s[hh*64+c] (same for adst).
// Block: 256 thr, 32 rows/block (8 rows/wave), lane l computes cols 2l,2l+1.
template<int K>
__global__ __launch_bounds__(256) void gemm_att_kernel(
    const float* __restrict__ in, const float* __restrict__ W,
    const float* __restrict__ att_s, const float* __restrict__ att_d,
    float* __restrict__ h, float* __restrict__ asrc, float* __restrict__ adst, int n)
{
  __shared__ float sW[64*128];   // k-tile of W (32 KB)
  __shared__ float sX[32*K];     // full-K x tile (<=16 KB)
  int t = threadIdx.x;
  int row0 = blockIdx.x*32;
  {
    const float4* X4 = (const float4*)(in + (size_t)row0*K);
    float4* sX4 = (float4*)sX;
    const int nx = 32*K/4;
    if(row0 + 32 <= n){
      for(int i = t; i < nx; i += 256) sX4[i] = X4[i];
    } else {
      for(int i = t; i < nx; i += 256){
        int r = row0 + i/(K/4);
        sX4[i] = (r < n) ? X4[i] : make_float4(0.f,0.f,0.f,0.f);
      }
    }
  }
  int lane = t & 63, wave = t >> 6;
  int r0 = wave*8;
  float2 acc[8];
  #pragma unroll
  for(int r = 0; r < 8; r++) acc[r] = make_float2(0.f, 0.f);

  for(int kt = 0; kt < K; kt += 64){
    __syncthreads();
    {
      const float4* W4 = (const float4*)(W + kt*128);
      float4* sW4 = (float4*)sW;
      for(int i = t; i < 2048; i += 256) sW4[i] = W4[i];
    }
    __syncthreads();
    const float2* sW2 = (const float2*)sW;
    for(int k = 0; k < 64; k += 2){
      float2 w0 = sW2[k*64 + lane];
      float2 w1 = sW2[(k+1)*64 + lane];
      #pragma unroll
      for(int r = 0; r < 8; r++){
        float2 xv = *(const float2*)&sX[(r0+r)*K + kt + k];
        acc[r].x = fmaf(xv.x, w0.x, acc[r].x);
        acc[r].x = fmaf(xv.y, w1.x, acc[r].x);
        acc[r].y = fmaf(xv.x, w0.y, acc[r].y);
        acc[r].y = fmaf(xv.y, w1.y, acc[r].y);
      }
    }
  }
  float2 as = ((const float2*)att_s)[lane];
  float2 ad = ((const float2*)att_d)[lane];
  #pragma unroll
  for(int r = 0; r < 8; r++){
    int row = row0 + r0 + r;
    if(row >= n) break;                         // wave-uniform
    ((float2*)(h + (size_t)row*128))[lane] = acc[r];
    float ps = acc[r].x*as.x + acc[r].y*as.y;
    float pd = acc[r].x*ad.x + acc[r].y*ad.y;
    #pragma unroll
    for(int m = 1; m < 32; m <<= 1){ ps += __shfl_xor(ps, m); pd += __shfl_xor(pd, m); }
    if(lane == 0)      { asrc[2*row]   = ps; adst[2*row]   = pd; }
    else if(lane == 32){ asrc[2*row+1] = ps; adst[2*row+1] = pd; }
  }
}

// ---------------- per-node softmax + aggregation (wave per node) ----------------
// lane l: float2 of h row at offset 2l -> lanes 0..31 head0 ch(2l,2l+1), lanes 32..63 head1.
// LAYER==1: out[n][64] = relu(mean_heads + bias). LAYER==2: out[n] = relu(mean+bias) . fcW + fcb.
template<int LAYER>
__global__ __launch_bounds__(256) void aggregate_kernel(
    const float* __restrict__ h, const float* __restrict__ asrc, const float* __restrict__ adst,
    const int* __restrict__ rowptr, const int* __restrict__ esrc,
    const float* __restrict__ bias, const float* __restrict__ fcW, const float* __restrict__ fcb,
    float* __restrict__ out, int n)
{
  int lane = threadIdx.x & 63;
  int node = blockIdx.x*4 + (threadIdx.x >> 6);
  if(node >= n) return;
  int beg = rowptr[node], end = rowptr[node+1];
  float2 adn = ((const float2*)adst)[node];

  // phase 1: softmax denominators; cache first-64 per-edge weights/srcs in registers
  float s0 = 0.f, s1 = 0.f, sw0 = 0.f, sw1 = 0.f;
  int ssrc = 0;
  int i = beg + lane;
  if(i < end){
    int s = esrc[i];
    float2 av = ((const float2*)asrc)[s];
    float e0 = av.x + adn.x; e0 = (e0 > 0.f) ? e0 : 0.2f*e0;
    float e1 = av.y + adn.y; e1 = (e1 > 0.f) ? e1 : 0.2f*e1;
    sw0 = __expf(e0); sw1 = __expf(e1);
    ssrc = s;
    s0 = sw0; s1 = sw1;
    for(i += 64; i < end; i += 64){
      int s2 = esrc[i];
      float2 av2 = ((const float2*)asrc)[s2];
      float f0 = av2.x + adn.x; f0 = (f0 > 0.f) ? f0 : 0.2f*f0;
      float f1 = av2.y + adn.y; f1 = (f1 > 0.f) ? f1 : 0.2f*f1;
      s0 += __expf(f0); s1 += __expf(f1);
    }
  }
  #pragma unroll
  for(int m = 1; m < 64; m <<= 1){ s0 += __shfl_xor(s0, m); s1 += __shfl_xor(s1, m); }

  int head = lane >> 5;
  float inv = 1.f/((head ? s1 : s0) + 1e-16f);
  float2 acc = make_float2(0.f, 0.f);
  int deg = end - beg;
  int m64 = deg < 64 ? deg : 64;
  #pragma unroll 4
  for(int j = 0; j < m64; j++){
    float v0 = __shfl(sw0, j);
    float v1 = __shfl(sw1, j);
    int   s  = __shfl(ssrc, j);
    float alpha = (head ? v1 : v0) * inv;
    float2 hv = ((const float2*)(h + (size_t)s*128))[lane];
    acc.x = fmaf(alpha, hv.x, acc.x);
    acc.y = fmaf(alpha, hv.y, acc.y);
  }
  // rare tail (deg > 64)
  float adh = head ? adn.y : adn.x;
  for(int i2 = beg + 64; i2 < end; i2++){
    int s = esrc[i2];
    float a = asrc[2*s + head];
    float e = a + adh; e = (e > 0.f) ? e : 0.2f*e;
    float alpha = __expf(e) * inv;
    float2 hv = ((const float2*)(h + (size_t)s*128))[lane];
    acc.x = fmaf(alpha, hv.x, acc.x);
    acc.y = fmaf(alpha, hv.y, acc.y);
  }

  float ox = acc.x + __shfl_xor(acc.x, 32);   // head0 + head1
  float oy = acc.y + __shfl_xor(acc.y, 32);
  if(LAYER == 1){
    if(lane < 32){
      float2 b = ((const float2*)bias)[lane];
      float v0 = fmaxf(fmaf(0.5f, ox, b.x), 0.f);
      float v1 = fmaxf(fmaf(0.5f, oy, b.y), 0.f);
      ((float2*)(out + (size_t)node*64))[lane] = make_float2(v0, v1);
    }
  } else {
    float p = 0.f;
    if(lane < 32){
      float2 b = ((const float2*)bias)[lane];
      float v0 = fmaxf(fmaf(0.5f, ox, b.x), 0.f);
      float v1 = fmaxf(fmaf(0.5f, oy, b.y), 0.f);
      float2 w = ((const float2*)fcW)[lane];
      p = fmaf(v0, w.x, v1*w.y);
    }
    #pragma unroll
    for(int m = 1; m < 32; m <<= 1) p += __shfl_xor(p, m);
    if(lane == 0) out[node] = p + fcb[0];
  }
}

// ---------------- launch ----------------
extern "C" void kernel_launch(void* const* d_in, const int* in_sizes, int n_in,
                              void* d_out, int out_size, void* d_ws, size_t ws_size,
                              hipStream_t stream)
{
  const float* x   = (const float*)d_in[0];
  const int*   ei  = (const int*)  d_in[1];
  const float* W1  = (const float*)d_in[2];
  const float* as1 = (const float*)d_in[3];
  const float* ad1 = (const float*)d_in[4];
  const float* b1  = (const float*)d_in[5];
  const float* W2  = (const float*)d_in[6];
  const float* as2 = (const float*)d_in[7];
  const float* ad2 = (const float*)d_in[8];
  const float* b2  = (const float*)d_in[9];
  const float* fcW = (const float*)d_in[10];
  const float* fcb = (const float*)d_in[11];
  float* out = (float*)d_out;

  char* ws = (char*)d_ws;
  size_t off = 0;
  auto alloc = [&](size_t bytes) -> void* {
    void* p = ws + off;
    off += (bytes + 255) & ~(size_t)255;
    return p;
  };
  int*   rowptr   = (int*)  alloc((NNODES+1)*sizeof(int));
  int*   cursor   = (int*)  alloc((NNODES+1)*sizeof(int));
  int*   partials = (int*)  alloc(256*sizeof(int));
  int*   esrc     = (int*)  alloc((size_t)EP*sizeof(int));
  float* h        = (float*)alloc((size_t)NNODES*128*sizeof(float));
  float* asrc     = (float*)alloc((size_t)NNODES*2*sizeof(float));
  float* adst     = (float*)alloc((size_t)NNODES*2*sizeof(float));
  float* out1     = (float*)alloc((size_t)NNODES*64*sizeof(float));

  const int SCAN_N = NNODES + 1;
  const int nchunks = (SCAN_N + 1023)/1024;   // 49

  hipLaunchKernelGGL(zero_kernel,    dim3((SCAN_N+255)/256), dim3(256), 0, stream, rowptr, SCAN_N);
  hipLaunchKernelGGL(hist_kernel,    dim3((EP+255)/256),     dim3(256), 0, stream, ei, rowptr);
  hipLaunchKernelGGL(scan1_kernel,   dim3(nchunks),          dim3(256), 0, stream, rowptr, partials, SCAN_N);
  hipLaunchKernelGGL(scan2_kernel,   dim3(1),                dim3(256), 0, stream, partials, nchunks);
  hipLaunchKernelGGL(scan3_kernel,   dim3(nchunks),          dim3(256), 0, stream, rowptr, partials, cursor, SCAN_N);
  hipLaunchKernelGGL(scatter_kernel, dim3((EP+255)/256),     dim3(256), 0, stream, ei, cursor, esrc);

  hipLaunchKernelGGL((gemm_att_kernel<128>), dim3((NNODES+31)/32), dim3(256), 0, stream,
                     x, W1, as1, ad1, h, asrc, adst, NNODES);
  hipLaunchKernelGGL((aggregate_kernel<1>),  dim3((NNODES+3)/4),   dim3(256), 0, stream,
                     h, asrc, adst, rowptr, esrc, b1, (const float*)nullptr, (const float*)nullptr, out1, NNODES);
  hipLaunchKernelGGL((gemm_att_kernel<64>),  dim3((NNODES+31)/32), dim3(256), 0, stream,
                     out1, W2, as2, ad2, h, asrc, adst, NNODES);
  hipLaunchKernelGGL((aggregate_kernel<2>),  dim3((NNODES+3)/4),   dim3(256), 0, stream,
                     h, asrc, adst, rowptr, esrc, b2, fcW, fcb, out, NNODES);
}

// Round 2
// 374.736 us; speedup vs baseline: 1.0394x; 1.0394x over previous
//
#include <hip/hip_runtime.h>
#include <hip/hip_fp16.h>

#define NNODES 50000
#define NEDGES 800000
#define EP (NEDGES + NNODES)   // 850000 edges incl. self-loops

// ---------------- CSR build ----------------
__global__ __launch_bounds__(256) void hist_kernel(const int* __restrict__ ei, int* __restrict__ deg){
  int e = blockIdx.x*256 + threadIdx.x;
  if(e >= EP) return;
  int d = (e < NEDGES) ? ei[NEDGES + e] : (e - NEDGES);
  atomicAdd(&deg[d], 1);
}

// chunk=1024 per block (4 elems/thread), exclusive scan in place, block totals -> partials
__global__ __launch_bounds__(256) void scan1_kernel(int* __restrict__ data, int* __restrict__ partials, int n){
  __shared__ int sm[256];
  int t = threadIdx.x;
  int base = blockIdx.x*1024 + t*4;
  int v0 = (base+0 < n) ? data[base+0] : 0;
  int v1 = (base+1 < n) ? data[base+1] : 0;
  int v2 = (base+2 < n) ? data[base+2] : 0;
  int v3 = (base+3 < n) ? data[base+3] : 0;
  int s = v0+v1+v2+v3;
  sm[t] = s;
  __syncthreads();
  int acc = s;
  #pragma unroll
  for(int d = 1; d < 256; d <<= 1){
    int o = (t >= d) ? sm[t-d] : 0;
    __syncthreads();
    acc += o;
    sm[t] = acc;
    __syncthreads();
  }
  int excl = acc - s;
  if(base+0 < n) data[base+0] = excl;
  if(base+1 < n) data[base+1] = excl + v0;
  if(base+2 < n) data[base+2] = excl + v0 + v1;
  if(base+3 < n) data[base+3] = excl + v0 + v1 + v2;
  if(t == 255) partials[blockIdx.x] = acc;
}

__global__ __launch_bounds__(256) void scan2_kernel(int* __restrict__ partials, int nb){
  __shared__ int sm[256];
  int t = threadIdx.x;
  int s = (t < nb) ? partials[t] : 0;
  sm[t] = s;
  __syncthreads();
  int acc = s;
  #pragma unroll
  for(int d = 1; d < 256; d <<= 1){
    int o = (t >= d) ? sm[t-d] : 0;
    __syncthreads();
    acc += o;
    sm[t] = acc;
    __syncthreads();
  }
  if(t < nb) partials[t] = acc - s;
}

__global__ __launch_bounds__(256) void scan3_kernel(int* __restrict__ data, const int* __restrict__ partials,
                                                    int* __restrict__ cursor, int n){
  int off = partials[blockIdx.x];
  for(int j = threadIdx.x; j < 1024; j += 256){
    int i = blockIdx.x*1024 + j;
    if(i < n){ int v = data[i] + off; data[i] = v; cursor[i] = v; }
  }
}

__global__ __launch_bounds__(256) void scatter_kernel(const int* __restrict__ ei, int* __restrict__ cursor,
                                                      int* __restrict__ esrc){
  int e = blockIdx.x*256 + threadIdx.x;
  if(e >= EP) return;
  int s, d;
  if(e < NEDGES){ s = ei[e]; d = ei[NEDGES + e]; }
  else          { s = d = e - NEDGES; }
  int pos = atomicAdd(&cursor[d], 1);
  esrc[pos] = s;
}

// ---------------- GEMM + attention-score epilogue ----------------
// h16[n][128] (fp16) = in[n][0:K] @ W[K][128]; asrc/adst[n][hh] = fp32 attn dots.
// Block: 256 thr, 32 rows/block (8 rows/wave), lane l computes cols 2l,2l+1.
template<int K>
__global__ __launch_bounds__(256) void gemm_att_kernel(
    const float* __restrict__ in, const float* __restrict__ W,
    const float* __restrict__ att_s, const float* __restrict__ att_d,
    __half2* __restrict__ h16, float* __restrict__ asrc, float* __restrict__ adst, int n)
{
  __shared__ __align__(16) float sW[64*128];   // k-tile of W (32 KB)
  __shared__ __align__(16) float sX[32*K];     // full-K x tile (<=16 KB)
  int t = threadIdx.x;
  int row0 = blockIdx.x*32;
  {
    const float4* X4 = (const float4*)(in + (size_t)row0*K);
    float4* sX4 = (float4*)sX;
    const int nx = 32*K/4;
    if(row0 + 32 <= n){
      for(int i = t; i < nx; i += 256) sX4[i] = X4[i];
    } else {
      for(int i = t; i < nx; i += 256){
        int r = row0 + i/(K/4);
        sX4[i] = (r < n) ? X4[i] : make_float4(0.f,0.f,0.f,0.f);
      }
    }
  }
  int lane = t & 63, wave = t >> 6;
  int r0 = wave*8;
  float2 acc[8];
  #pragma unroll
  for(int r = 0; r < 8; r++) acc[r] = make_float2(0.f, 0.f);

  for(int kt = 0; kt < K; kt += 64){
    __syncthreads();
    {
      const float4* W4 = (const float4*)(W + kt*128);
      float4* sW4 = (float4*)sW;
      for(int i = t; i < 2048; i += 256) sW4[i] = W4[i];
    }
    __syncthreads();
    const float2* sW2 = (const float2*)sW;
    for(int k = 0; k < 64; k += 4){
      float2 w0 = sW2[(k+0)*64 + lane];
      float2 w1 = sW2[(k+1)*64 + lane];
      float2 w2 = sW2[(k+2)*64 + lane];
      float2 w3 = sW2[(k+3)*64 + lane];
      #pragma unroll
      for(int r = 0; r < 8; r++){
        float4 xv = *(const float4*)&sX[(r0+r)*K + kt + k];
        acc[r].x = fmaf(xv.x, w0.x, acc[r].x);
        acc[r].y = fmaf(xv.x, w0.y, acc[r].y);
        acc[r].x = fmaf(xv.y, w1.x, acc[r].x);
        acc[r].y = fmaf(xv.y, w1.y, acc[r].y);
        acc[r].x = fmaf(xv.z, w2.x, acc[r].x);
        acc[r].y = fmaf(xv.z, w2.y, acc[r].y);
        acc[r].x = fmaf(xv.w, w3.x, acc[r].x);
        acc[r].y = fmaf(xv.w, w3.y, acc[r].y);
      }
    }
  }
  float2 as = ((const float2*)att_s)[lane];
  float2 ad = ((const float2*)att_d)[lane];
  #pragma unroll
  for(int r = 0; r < 8; r++){
    int row = row0 + r0 + r;
    if(row >= n) break;                         // wave-uniform
    h16[(size_t)row*64 + lane] = __float22half2_rn(acc[r]);
    float ps = acc[r].x*as.x + acc[r].y*as.y;
    float pd = acc[r].x*ad.x + acc[r].y*ad.y;
    #pragma unroll
    for(int m = 1; m < 32; m <<= 1){ ps += __shfl_xor(ps, m); pd += __shfl_xor(pd, m); }
    if(lane == 0)      { asrc[2*row]   = ps; adst[2*row]   = pd; }
    else if(lane == 32){ asrc[2*row+1] = ps; adst[2*row+1] = pd; }
  }
}

// ---------------- per-node softmax + aggregation (wave per node) ----------------
// lane l: __half2 of h row at channel offset 2l -> lanes 0..31 head0, 32..63 head1.
// LAYER==1: out[n][64] = relu(mean_heads + bias). LAYER==2: out[n] = relu(mean+bias) . fcW + fcb.
template<int LAYER>
__global__ __launch_bounds__(256) void aggregate_kernel(
    const __half2* __restrict__ h16, const float* __restrict__ asrc, const float* __restrict__ adst,
    const int* __restrict__ rowptr, const int* __restrict__ esrc,
    const float* __restrict__ bias, const float* __restrict__ fcW, const float* __restrict__ fcb,
    float* __restrict__ out, int n)
{
  int lane = threadIdx.x & 63;
  int node = blockIdx.x*4 + (threadIdx.x >> 6);
  if(node >= n) return;
  int beg = rowptr[node], end = rowptr[node+1];
  float2 adn = ((const float2*)adst)[node];

  // phase 1: softmax denominators; cache first-64 per-edge weights/srcs in registers
  float s0 = 0.f, s1 = 0.f, sw0 = 0.f, sw1 = 0.f;
  int ssrc = 0;
  int i = beg + lane;
  if(i < end){
    int s = esrc[i];
    float2 av = ((const float2*)asrc)[s];
    float e0 = av.x + adn.x; e0 = (e0 > 0.f) ? e0 : 0.2f*e0;
    float e1 = av.y + adn.y; e1 = (e1 > 0.f) ? e1 : 0.2f*e1;
    sw0 = __expf(e0); sw1 = __expf(e1);
    ssrc = s;
    s0 = sw0; s1 = sw1;
    for(i += 64; i < end; i += 64){
      int s2 = esrc[i];
      float2 av2 = ((const float2*)asrc)[s2];
      float f0 = av2.x + adn.x; f0 = (f0 > 0.f) ? f0 : 0.2f*f0;
      float f1 = av2.y + adn.y; f1 = (f1 > 0.f) ? f1 : 0.2f*f1;
      s0 += __expf(f0); s1 += __expf(f1);
    }
  }
  #pragma unroll
  for(int m = 1; m < 64; m <<= 1){ s0 += __shfl_xor(s0, m); s1 += __shfl_xor(s1, m); }

  int head = lane >> 5;
  float inv = 1.f/((head ? s1 : s0) + 1e-16f);
  float2 acc = make_float2(0.f, 0.f);
  int deg = end - beg;
  int m64 = deg < 64 ? deg : 64;
  #pragma unroll 4
  for(int j = 0; j < m64; j++){
    float v0 = __shfl(sw0, j);
    float v1 = __shfl(sw1, j);
    int   s  = __shfl(ssrc, j);
    float alpha = (head ? v1 : v0) * inv;
    float2 hv = __half22float2(h16[(size_t)s*64 + lane]);
    acc.x = fmaf(alpha, hv.x, acc.x);
    acc.y = fmaf(alpha, hv.y, acc.y);
  }
  // rare tail (deg > 64)
  float adh = head ? adn.y : adn.x;
  for(int i2 = beg + 64; i2 < end; i2++){
    int s = esrc[i2];
    float a = asrc[2*s + head];
    float e = a + adh; e = (e > 0.f) ? e : 0.2f*e;
    float alpha = __expf(e) * inv;
    float2 hv = __half22float2(h16[(size_t)s*64 + lane]);
    acc.x = fmaf(alpha, hv.x, acc.x);
    acc.y = fmaf(alpha, hv.y, acc.y);
  }

  float ox = acc.x + __shfl_xor(acc.x, 32);   // head0 + head1
  float oy = acc.y + __shfl_xor(acc.y, 32);
  if(LAYER == 1){
    if(lane < 32){
      float2 b = ((const float2*)bias)[lane];
      float v0 = fmaxf(fmaf(0.5f, ox, b.x), 0.f);
      float v1 = fmaxf(fmaf(0.5f, oy, b.y), 0.f);
      ((float2*)(out + (size_t)node*64))[lane] = make_float2(v0, v1);
    }
  } else {
    float p = 0.f;
    if(lane < 32){
      float2 b = ((const float2*)bias)[lane];
      float v0 = fmaxf(fmaf(0.5f, ox, b.x), 0.f);
      float v1 = fmaxf(fmaf(0.5f, oy, b.y), 0.f);
      float2 w = ((const float2*)fcW)[lane];
      p = fmaf(v0, w.x, v1*w.y);
    }
    #pragma unroll
    for(int m = 1; m < 32; m <<= 1) p += __shfl_xor(p, m);
    if(lane == 0) out[node] = p + fcb[0];
  }
}

// ---------------- launch ----------------
extern "C" void kernel_launch(void* const* d_in, const int* in_sizes, int n_in,
                              void* d_out, int out_size, void* d_ws, size_t ws_size,
                              hipStream_t stream)
{
  const float* x   = (const float*)d_in[0];
  const int*   ei  = (const int*)  d_in[1];
  const float* W1  = (const float*)d_in[2];
  const float* as1 = (const float*)d_in[3];
  const float* ad1 = (const float*)d_in[4];
  const float* b1  = (const float*)d_in[5];
  const float* W2  = (const float*)d_in[6];
  const float* as2 = (const float*)d_in[7];
  const float* ad2 = (const float*)d_in[8];
  const float* b2  = (const float*)d_in[9];
  const float* fcW = (const float*)d_in[10];
  const float* fcb = (const float*)d_in[11];
  float* out = (float*)d_out;

  char* ws = (char*)d_ws;
  size_t off = 0;
  auto alloc = [&](size_t bytes) -> void* {
    void* p = ws + off;
    off += (bytes + 255) & ~(size_t)255;
    return p;
  };
  int*     rowptr   = (int*)    alloc((NNODES+1)*sizeof(int));
  int*     cursor   = (int*)    alloc((NNODES+1)*sizeof(int));
  int*     partials = (int*)    alloc(256*sizeof(int));
  int*     esrc     = (int*)    alloc((size_t)EP*sizeof(int));
  __half2* h16      = (__half2*)alloc((size_t)NNODES*64*sizeof(__half2));
  float*   asrc     = (float*)  alloc((size_t)NNODES*2*sizeof(float));
  float*   adst     = (float*)  alloc((size_t)NNODES*2*sizeof(float));
  float*   out1     = (float*)  alloc((size_t)NNODES*64*sizeof(float));

  const int SCAN_N = NNODES + 1;
  const int nchunks = (SCAN_N + 1023)/1024;   // 49

  hipMemsetAsync(rowptr, 0, SCAN_N*sizeof(int), stream);
  hipLaunchKernelGGL(hist_kernel,    dim3((EP+255)/256),     dim3(256), 0, stream, ei, rowptr);
  hipLaunchKernelGGL(scan1_kernel,   dim3(nchunks),          dim3(256), 0, stream, rowptr, partials, SCAN_N);
  hipLaunchKernelGGL(scan2_kernel,   dim3(1),                dim3(256), 0, stream, partials, nchunks);
  hipLaunchKernelGGL(scan3_kernel,   dim3(nchunks),          dim3(256), 0, stream, rowptr, partials, cursor, SCAN_N);
  hipLaunchKernelGGL(scatter_kernel, dim3((EP+255)/256),     dim3(256), 0, stream, ei, cursor, esrc);

  hipLaunchKernelGGL((gemm_att_kernel<128>), dim3((NNODES+31)/32), dim3(256), 0, stream,
                     x, W1, as1, ad1, h16, asrc, adst, NNODES);
  hipLaunchKernelGGL((aggregate_kernel<1>),  dim3((NNODES+3)/4),   dim3(256), 0, stream,
                     h16, asrc, adst, rowptr, esrc, b1, (const float*)nullptr, (const float*)nullptr, out1, NNODES);
  hipLaunchKernelGGL((gemm_att_kernel<64>),  dim3((NNODES+31)/32), dim3(256), 0, stream,
                     out1, W2, as2, ad2, h16, asrc, adst, NNODES);
  hipLaunchKernelGGL((aggregate_kernel<2>),  dim3((NNODES+3)/4),   dim3(256), 0, stream,
                     h16, asrc, adst, rowptr, esrc, b2, fcW, fcb, out, NNODES);
}

// Round 3
// 314.821 us; speedup vs baseline: 1.2373x; 1.1903x over previous
//
#include <hip/hip_runtime.h>
#include <hip/hip_fp16.h>

#define NNODES 50000
#define NEDGES 800000
#define EP (NEDGES + NNODES)   // 850000 edges incl. self-loops
#define CAP 64                 // per-node LDS edge cache (Poisson(17): P(deg>64) ~ 0)

// ---------------- CSR build ----------------
__global__ __launch_bounds__(256) void hist_kernel(const int* __restrict__ ei, int* __restrict__ deg){
  int e = blockIdx.x*256 + threadIdx.x;
  if(e >= EP) return;
  int d = (e < NEDGES) ? ei[NEDGES + e] : (e - NEDGES);
  atomicAdd(&deg[d], 1);
}

__global__ __launch_bounds__(256) void scan1_kernel(int* __restrict__ data, int* __restrict__ partials, int n){
  __shared__ int sm[256];
  int t = threadIdx.x;
  int base = blockIdx.x*1024 + t*4;
  int v0 = (base+0 < n) ? data[base+0] : 0;
  int v1 = (base+1 < n) ? data[base+1] : 0;
  int v2 = (base+2 < n) ? data[base+2] : 0;
  int v3 = (base+3 < n) ? data[base+3] : 0;
  int s = v0+v1+v2+v3;
  sm[t] = s;
  __syncthreads();
  int acc = s;
  #pragma unroll
  for(int d = 1; d < 256; d <<= 1){
    int o = (t >= d) ? sm[t-d] : 0;
    __syncthreads();
    acc += o;
    sm[t] = acc;
    __syncthreads();
  }
  int excl = acc - s;
  if(base+0 < n) data[base+0] = excl;
  if(base+1 < n) data[base+1] = excl + v0;
  if(base+2 < n) data[base+2] = excl + v0 + v1;
  if(base+3 < n) data[base+3] = excl + v0 + v1 + v2;
  if(t == 255) partials[blockIdx.x] = acc;
}

__global__ __launch_bounds__(256) void scan2_kernel(int* __restrict__ partials, int nb){
  __shared__ int sm[256];
  int t = threadIdx.x;
  int s = (t < nb) ? partials[t] : 0;
  sm[t] = s;
  __syncthreads();
  int acc = s;
  #pragma unroll
  for(int d = 1; d < 256; d <<= 1){
    int o = (t >= d) ? sm[t-d] : 0;
    __syncthreads();
    acc += o;
    sm[t] = acc;
    __syncthreads();
  }
  if(t < nb) partials[t] = acc - s;
}

__global__ __launch_bounds__(256) void scan3_kernel(int* __restrict__ data, const int* __restrict__ partials,
                                                    int* __restrict__ cursor, int n){
  int off = partials[blockIdx.x];
  for(int j = threadIdx.x; j < 1024; j += 256){
    int i = blockIdx.x*1024 + j;
    if(i < n){ int v = data[i] + off; data[i] = v; cursor[i] = v; }
  }
}

__global__ __launch_bounds__(256) void scatter_kernel(const int* __restrict__ ei, int* __restrict__ cursor,
                                                      int* __restrict__ esrc){
  int e = blockIdx.x*256 + threadIdx.x;
  if(e >= EP) return;
  int s, d;
  if(e < NEDGES){ s = ei[e]; d = ei[NEDGES + e]; }
  else          { s = d = e - NEDGES; }
  int pos = atomicAdd(&cursor[d], 1);
  esrc[pos] = s;
}

// ---------------- GEMM + attention-score epilogue ----------------
// h16[n][128] (fp16, row-major) = in[n][0:K] @ W[K][128]; asrc/adst fp32 [n][2].
template<int K>
__global__ __launch_bounds__(256) void gemm_att_kernel(
    const float* __restrict__ in, const float* __restrict__ W,
    const float* __restrict__ att_s, const float* __restrict__ att_d,
    __half2* __restrict__ h16, float* __restrict__ asrc, float* __restrict__ adst, int n)
{
  __shared__ __align__(16) float sW[64*128];   // 32 KB
  __shared__ __align__(16) float sX[32*K];     // <=16 KB
  int t = threadIdx.x;
  int row0 = blockIdx.x*32;
  {
    const float4* X4 = (const float4*)(in + (size_t)row0*K);
    float4* sX4 = (float4*)sX;
    const int nx = 32*K/4;
    if(row0 + 32 <= n){
      for(int i = t; i < nx; i += 256) sX4[i] = X4[i];
    } else {
      for(int i = t; i < nx; i += 256){
        int r = row0 + i/(K/4);
        sX4[i] = (r < n) ? X4[i] : make_float4(0.f,0.f,0.f,0.f);
      }
    }
  }
  int lane = t & 63, wave = t >> 6;
  int r0 = wave*8;
  float2 acc[8];
  #pragma unroll
  for(int r = 0; r < 8; r++) acc[r] = make_float2(0.f, 0.f);

  for(int kt = 0; kt < K; kt += 64){
    __syncthreads();
    {
      const float4* W4 = (const float4*)(W + kt*128);
      float4* sW4 = (float4*)sW;
      for(int i = t; i < 2048; i += 256) sW4[i] = W4[i];
    }
    __syncthreads();
    const float2* sW2 = (const float2*)sW;
    for(int k = 0; k < 64; k += 4){
      float2 w0 = sW2[(k+0)*64 + lane];
      float2 w1 = sW2[(k+1)*64 + lane];
      float2 w2 = sW2[(k+2)*64 + lane];
      float2 w3 = sW2[(k+3)*64 + lane];
      #pragma unroll
      for(int r = 0; r < 8; r++){
        float4 xv = *(const float4*)&sX[(r0+r)*K + kt + k];
        acc[r].x = fmaf(xv.x, w0.x, acc[r].x);
        acc[r].y = fmaf(xv.x, w0.y, acc[r].y);
        acc[r].x = fmaf(xv.y, w1.x, acc[r].x);
        acc[r].y = fmaf(xv.y, w1.y, acc[r].y);
        acc[r].x = fmaf(xv.z, w2.x, acc[r].x);
        acc[r].y = fmaf(xv.z, w2.y, acc[r].y);
        acc[r].x = fmaf(xv.w, w3.x, acc[r].x);
        acc[r].y = fmaf(xv.w, w3.y, acc[r].y);
      }
    }
  }
  float2 as = ((const float2*)att_s)[lane];
  float2 ad = ((const float2*)att_d)[lane];
  #pragma unroll
  for(int r = 0; r < 8; r++){
    int row = row0 + r0 + r;
    if(row >= n) break;                         // wave-uniform
    h16[(size_t)row*64 + lane] = __float22half2_rn(acc[r]);
    float ps = acc[r].x*as.x + acc[r].y*as.y;
    float pd = acc[r].x*ad.x + acc[r].y*ad.y;
    #pragma unroll
    for(int m = 1; m < 32; m <<= 1){ ps += __shfl_xor(ps, m); pd += __shfl_xor(pd, m); }
    if(lane == 0)      { asrc[2*row]   = ps; adst[2*row]   = pd; }
    else if(lane == 32){ asrc[2*row+1] = ps; adst[2*row+1] = pd; }
  }
}

// ---------------- softmax + aggregation: 4 nodes/wave, 16 lanes/node ----------------
// lane p (0..15) of a node group reads h16 row bytes [16p,16p+16) = channels 8p..8p+7.
// p<8 -> head0, p>=8 -> head1. Per-edge (w0,w1,src) cached+normalized in LDS;
// phase 2: one broadcast ds_read_b128 + one dwordx4 gather (4 rows/wave-instr) per step.
template<int LAYER>
__global__ __launch_bounds__(256) void aggregate_kernel(
    const uint4* __restrict__ h16u4, const float2* __restrict__ asrc2, const float2* __restrict__ adst2,
    const int* __restrict__ rowptr, const int* __restrict__ esrc,
    const float* __restrict__ bias, const float* __restrict__ fcW, const float* __restrict__ fcb,
    float* __restrict__ out, int n)
{
  __shared__ float4 sE[16][CAP+1];    // +1 row pad: cross-group bank aliasing -> free 2-way
  int t = threadIdx.x;
  int p = t & 15;                      // position within node group
  int slot = t >> 4;                   // node slot in block (0..15)
  int node = blockIdx.x*16 + slot;
  bool valid = node < n;
  int nd = valid ? node : 0;
  int beg = rowptr[nd], end = rowptr[nd+1];
  if(!valid){ beg = 0; end = 0; }
  float2 adn = adst2[nd];

  // phase 1: exp(leakyrelu) weights + partial sums; cache first CAP edges in LDS
  float s0 = 0.f, s1 = 0.f;
  for(int i = beg + p; i < end; i += 16){
    int s = esrc[i];
    float2 av = asrc2[s];
    float e0 = av.x + adn.x; e0 = (e0 > 0.f) ? e0 : 0.2f*e0;
    float e1 = av.y + adn.y; e1 = (e1 > 0.f) ? e1 : 0.2f*e1;
    float w0 = __expf(e0), w1 = __expf(e1);
    s0 += w0; s1 += w1;
    int j = i - beg;
    if(j < CAP) sE[slot][j] = make_float4(w0, w1, __int_as_float(s), 0.f);
  }
  #pragma unroll
  for(int m = 1; m < 16; m <<= 1){ s0 += __shfl_xor(s0, m); s1 += __shfl_xor(s1, m); }
  float inv0 = 1.f/(s0 + 1e-16f), inv1 = 1.f/(s1 + 1e-16f);

  int deg = end - beg;
  int dcap = deg < CAP ? deg : CAP;
  // normalize in place (same lane wrote these entries)
  for(int j = p; j < dcap; j += 16){
    float4 e = sE[slot][j];
    e.x *= inv0; e.y *= inv1;
    sE[slot][j] = e;
  }
  int maxd = dcap;
  maxd = max(maxd, __shfl_xor(maxd, 16));
  maxd = max(maxd, __shfl_xor(maxd, 32));

  bool head1 = p >= 8;
  float2 acc0 = make_float2(0.f,0.f), acc1 = acc0, acc2 = acc0, acc3 = acc0;

  #pragma unroll 4
  for(int j = 0; j < maxd; j++){
    float4 e = sE[slot][j];
    bool act = j < dcap;
    float alpha = act ? (head1 ? e.y : e.x) : 0.f;
    int s = act ? __float_as_int(e.z) : 0;
    uint4 hv = h16u4[(size_t)s*16 + p];
    const __half2 h0 = *(const __half2*)&hv.x;
    const __half2 h1 = *(const __half2*)&hv.y;
    const __half2 h2 = *(const __half2*)&hv.z;
    const __half2 h3 = *(const __half2*)&hv.w;
    acc0.x = fmaf(__half2float(h0.x), alpha, acc0.x);
    acc0.y = fmaf(__half2float(h0.y), alpha, acc0.y);
    acc1.x = fmaf(__half2float(h1.x), alpha, acc1.x);
    acc1.y = fmaf(__half2float(h1.y), alpha, acc1.y);
    acc2.x = fmaf(__half2float(h2.x), alpha, acc2.x);
    acc2.y = fmaf(__half2float(h2.y), alpha, acc2.y);
    acc3.x = fmaf(__half2float(h3.x), alpha, acc3.x);
    acc3.y = fmaf(__half2float(h3.y), alpha, acc3.y);
  }
  // tail deg > CAP (practically never)
  float inv_mine = head1 ? inv1 : inv0;
  float adh = head1 ? adn.y : adn.x;
  for(int i2 = beg + CAP; i2 < end; i2++){
    int s = esrc[i2];
    float2 av = asrc2[s];
    float e_ = (head1 ? av.y : av.x) + adh;
    e_ = (e_ > 0.f) ? e_ : 0.2f*e_;
    float alpha = __expf(e_) * inv_mine;
    uint4 hv = h16u4[(size_t)s*16 + p];
    const __half2 h0 = *(const __half2*)&hv.x;
    const __half2 h1 = *(const __half2*)&hv.y;
    const __half2 h2 = *(const __half2*)&hv.z;
    const __half2 h3 = *(const __half2*)&hv.w;
    acc0.x = fmaf(__half2float(h0.x), alpha, acc0.x);
    acc0.y = fmaf(__half2float(h0.y), alpha, acc0.y);
    acc1.x = fmaf(__half2float(h1.x), alpha, acc1.x);
    acc1.y = fmaf(__half2float(h1.y), alpha, acc1.y);
    acc2.x = fmaf(__half2float(h2.x), alpha, acc2.x);
    acc2.y = fmaf(__half2float(h2.y), alpha, acc2.y);
    acc3.x = fmaf(__half2float(h3.x), alpha, acc3.x);
    acc3.y = fmaf(__half2float(h3.y), alpha, acc3.y);
  }

  // head mean: partner lane p^8 holds the other head's same channels
  float o0 = acc0.x + __shfl_xor(acc0.x, 8);
  float o1 = acc0.y + __shfl_xor(acc0.y, 8);
  float o2 = acc1.x + __shfl_xor(acc1.x, 8);
  float o3 = acc1.y + __shfl_xor(acc1.y, 8);
  float o4 = acc2.x + __shfl_xor(acc2.x, 8);
  float o5 = acc2.y + __shfl_xor(acc2.y, 8);
  float o6 = acc3.x + __shfl_xor(acc3.x, 8);
  float o7 = acc3.y + __shfl_xor(acc3.y, 8);

  if(LAYER == 1){
    if(!head1 && valid){
      float4 b0 = ((const float4*)bias)[2*p];
      float4 b1 = ((const float4*)bias)[2*p+1];
      float4 r0 = make_float4(fmaxf(fmaf(0.5f,o0,b0.x),0.f), fmaxf(fmaf(0.5f,o1,b0.y),0.f),
                              fmaxf(fmaf(0.5f,o2,b0.z),0.f), fmaxf(fmaf(0.5f,o3,b0.w),0.f));
      float4 r1 = make_float4(fmaxf(fmaf(0.5f,o4,b1.x),0.f), fmaxf(fmaf(0.5f,o5,b1.y),0.f),
                              fmaxf(fmaf(0.5f,o6,b1.z),0.f), fmaxf(fmaf(0.5f,o7,b1.w),0.f));
      float4* orow = (float4*)(out + (size_t)node*64 + 8*p);
      orow[0] = r0; orow[1] = r1;
    }
  } else {
    float partial = 0.f;
    if(!head1){
      float4 b0 = ((const float4*)bias)[2*p];
      float4 b1 = ((const float4*)bias)[2*p+1];
      float4 w0 = ((const float4*)fcW)[2*p];
      float4 w1 = ((const float4*)fcW)[2*p+1];
      partial  = fmaxf(fmaf(0.5f,o0,b0.x),0.f)*w0.x + fmaxf(fmaf(0.5f,o1,b0.y),0.f)*w0.y
               + fmaxf(fmaf(0.5f,o2,b0.z),0.f)*w0.z + fmaxf(fmaf(0.5f,o3,b0.w),0.f)*w0.w
               + fmaxf(fmaf(0.5f,o4,b1.x),0.f)*w1.x + fmaxf(fmaf(0.5f,o5,b1.y),0.f)*w1.y
               + fmaxf(fmaf(0.5f,o6,b1.z),0.f)*w1.z + fmaxf(fmaf(0.5f,o7,b1.w),0.f)*w1.w;
    }
    partial += __shfl_xor(partial, 1);
    partial += __shfl_xor(partial, 2);
    partial += __shfl_xor(partial, 4);
    if(p == 0 && valid) out[node] = partial + fcb[0];
  }
}

// ---------------- launch ----------------
extern "C" void kernel_launch(void* const* d_in, const int* in_sizes, int n_in,
                              void* d_out, int out_size, void* d_ws, size_t ws_size,
                              hipStream_t stream)
{
  const float* x   = (const float*)d_in[0];
  const int*   ei  = (const int*)  d_in[1];
  const float* W1  = (const float*)d_in[2];
  const float* as1 = (const float*)d_in[3];
  const float* ad1 = (const float*)d_in[4];
  const float* b1  = (const float*)d_in[5];
  const float* W2  = (const float*)d_in[6];
  const float* as2 = (const float*)d_in[7];
  const float* ad2 = (const float*)d_in[8];
  const float* b2  = (const float*)d_in[9];
  const float* fcW = (const float*)d_in[10];
  const float* fcb = (const float*)d_in[11];
  float* out = (float*)d_out;

  char* ws = (char*)d_ws;
  size_t off = 0;
  auto alloc = [&](size_t bytes) -> void* {
    void* p = ws + off;
    off += (bytes + 255) & ~(size_t)255;
    return p;
  };
  int*     rowptr   = (int*)    alloc((NNODES+1)*sizeof(int));
  int*     cursor   = (int*)    alloc((NNODES+1)*sizeof(int));
  int*     partials = (int*)    alloc(256*sizeof(int));
  int*     esrc     = (int*)    alloc((size_t)EP*sizeof(int));
  __half2* h16      = (__half2*)alloc((size_t)NNODES*64*sizeof(__half2));
  float*   asrc     = (float*)  alloc((size_t)NNODES*2*sizeof(float));
  float*   adst     = (float*)  alloc((size_t)NNODES*2*sizeof(float));
  float*   out1     = (float*)  alloc((size_t)NNODES*64*sizeof(float));

  const int SCAN_N = NNODES + 1;
  const int nchunks = (SCAN_N + 1023)/1024;   // 49

  hipMemsetAsync(rowptr, 0, SCAN_N*sizeof(int), stream);
  hipLaunchKernelGGL(hist_kernel,    dim3((EP+255)/256),     dim3(256), 0, stream, ei, rowptr);
  hipLaunchKernelGGL(scan1_kernel,   dim3(nchunks),          dim3(256), 0, stream, rowptr, partials, SCAN_N);
  hipLaunchKernelGGL(scan2_kernel,   dim3(1),                dim3(256), 0, stream, partials, nchunks);
  hipLaunchKernelGGL(scan3_kernel,   dim3(nchunks),          dim3(256), 0, stream, rowptr, partials, cursor, SCAN_N);
  hipLaunchKernelGGL(scatter_kernel, dim3((EP+255)/256),     dim3(256), 0, stream, ei, cursor, esrc);

  hipLaunchKernelGGL((gemm_att_kernel<128>), dim3((NNODES+31)/32), dim3(256), 0, stream,
                     x, W1, as1, ad1, h16, asrc, adst, NNODES);
  hipLaunchKernelGGL((aggregate_kernel<1>),  dim3((NNODES+15)/16), dim3(256), 0, stream,
                     (const uint4*)h16, (const float2*)asrc, (const float2*)adst, rowptr, esrc,
                     b1, (const float*)nullptr, (const float*)nullptr, out1, NNODES);
  hipLaunchKernelGGL((gemm_att_kernel<64>),  dim3((NNODES+31)/32), dim3(256), 0, stream,
                     out1, W2, as2, ad2, h16, asrc, adst, NNODES);
  hipLaunchKernelGGL((aggregate_kernel<2>),  dim3((NNODES+15)/16), dim3(256), 0, stream,
                     (const uint4*)h16, (const float2*)asrc, (const float2*)adst, rowptr, esrc,
                     b2, fcW, fcb, out, NNODES);
}

// Round 4
// 261.894 us; speedup vs baseline: 1.4873x; 1.2021x over previous
//
#include <hip/hip_runtime.h>
#include <hip/hip_fp16.h>

#define NNODES 50000
#define NEDGES 800000
#define EP (NEDGES + NNODES)   // 850000 edges incl. self-loops
#define CAP 64                 // per-node LDS edge cache in aggregate
#define NB 196                 // dst buckets of 256 nodes: ceil(50000/256)
#define CHUNK 8192             // edges per partition block

// ---------------- CSR build: two-level counting sort ----------------
// Pass A1: global bucket histogram (LDS-aggregated)
__global__ __launch_bounds__(256) void bucket_hist_kernel(const int* __restrict__ ei, int* __restrict__ bucketHist){
  __shared__ int lh[NB];
  int t = threadIdx.x;
  for(int i = t; i < NB; i += 256) lh[i] = 0;
  __syncthreads();
  int base = blockIdx.x*CHUNK;
  #pragma unroll
  for(int k = 0; k < CHUNK; k += 256){
    int e = base + k + t;
    if(e < EP){
      int d = (e < NEDGES) ? ei[NEDGES + e] : (e - NEDGES);
      atomicAdd(&lh[d >> 8], 1);
    }
  }
  __syncthreads();
  for(int i = t; i < NB; i += 256) if(lh[i]) atomicAdd(&bucketHist[i], lh[i]);
}

// exclusive scan of NB bucket counts -> bucketBase[NB+1], bucketCursor; rowptr sentinel
__global__ __launch_bounds__(256) void bucket_scan_kernel(const int* __restrict__ bucketHist,
                                                          int* __restrict__ bucketBase,
                                                          int* __restrict__ bucketCursor,
                                                          int* __restrict__ rowptr){
  __shared__ int sb[256];
  int t = threadIdx.x;
  int v = (t < NB) ? bucketHist[t] : 0;
  sb[t] = v; __syncthreads();
  int acc = v;
  #pragma unroll
  for(int d = 1; d < 256; d <<= 1){
    int o = (t >= d) ? sb[t-d] : 0;
    __syncthreads();
    acc += o; sb[t] = acc;
    __syncthreads();
  }
  int excl = acc - v;
  if(t <= NB) bucketBase[t] = excl;          // bucketBase[NB] == EP
  if(t <  NB) bucketCursor[t] = excl;
  if(t == 0)  rowptr[NNODES] = EP;
}

// Pass A2: partition edges into buckets, packed pk = (d<<16)|s, LDS-staged coalesced flush
__global__ __launch_bounds__(256) void partition_kernel(const int* __restrict__ ei,
                                                        int* __restrict__ bucketCursor,
                                                        unsigned int* __restrict__ edgebuf){
  __shared__ unsigned int stage[CHUNK];      // 32 KB
  __shared__ int lh[NB], lbase[NB], lcur[NB], gbase[NB];
  __shared__ int sb[256];
  int t = threadIdx.x;
  for(int i = t; i < NB; i += 256) lh[i] = 0;
  __syncthreads();
  int base = blockIdx.x*CHUNK;
  unsigned int pk[CHUNK/256];
  #pragma unroll
  for(int k = 0; k < CHUNK/256; k++){
    int e = base + k*256 + t;
    unsigned int p = 0xffffffffu;            // sentinel: valid pk < 0xC3500000
    if(e < EP){
      int s, d;
      if(e < NEDGES){ s = ei[e]; d = ei[NEDGES + e]; }
      else          { s = d = e - NEDGES; }
      p = ((unsigned int)d << 16) | (unsigned int)s;
      atomicAdd(&lh[d >> 8], 1);
    }
    pk[k] = p;
  }
  __syncthreads();
  int v = (t < NB) ? lh[t] : 0;
  sb[t] = v; __syncthreads();
  int acc = v;
  #pragma unroll
  for(int d = 1; d < 256; d <<= 1){
    int o = (t >= d) ? sb[t-d] : 0;
    __syncthreads();
    acc += o; sb[t] = acc;
    __syncthreads();
  }
  int excl = acc - v;
  if(t < NB){
    lbase[t] = excl; lcur[t] = excl;
    gbase[t] = v ? atomicAdd(&bucketCursor[t], v) : 0;
  }
  __syncthreads();
  #pragma unroll
  for(int k = 0; k < CHUNK/256; k++){
    unsigned int p = pk[k];
    if(p != 0xffffffffu){
      int bin = p >> 24;
      int r = atomicAdd(&lcur[bin], 1);
      stage[r] = p;
    }
  }
  __syncthreads();
  int nvalid = EP - base; if(nvalid > CHUNK) nvalid = CHUNK;
  for(int j = t; j < nvalid; j += 256){
    unsigned int p = stage[j];
    int bin = p >> 24;
    edgebuf[gbase[bin] + (j - lbase[bin])] = p;   // coalesced runs (~42 edges/bin/block)
  }
}

// Pass B: one block per bucket -> rowptr + esrc (writes confined to ~17KB L2 window)
__global__ __launch_bounds__(256) void bucket_sort_kernel(const unsigned int* __restrict__ edgebuf,
                                                          const int* __restrict__ bucketBase,
                                                          int* __restrict__ rowptr,
                                                          int* __restrict__ esrc){
  __shared__ int lh[256], lcur[256], sb[256];
  int b = blockIdx.x, t = threadIdx.x;
  int lo = bucketBase[b], hi = bucketBase[b+1];
  lh[t] = 0;
  __syncthreads();
  for(int i = lo + t; i < hi; i += 256)
    atomicAdd(&lh[(edgebuf[i] >> 16) & 255], 1);
  __syncthreads();
  int v = lh[t];
  sb[t] = v; __syncthreads();
  int acc = v;
  #pragma unroll
  for(int d = 1; d < 256; d <<= 1){
    int o = (t >= d) ? sb[t-d] : 0;
    __syncthreads();
    acc += o; sb[t] = acc;
    __syncthreads();
  }
  int excl = acc - v;
  lcur[t] = lo + excl;
  int node = b*256 + t;
  if(node < NNODES) rowptr[node] = lo + excl;
  __syncthreads();
  for(int i = lo + t; i < hi; i += 256){
    unsigned int p = edgebuf[i];
    int pos = atomicAdd(&lcur[(p >> 16) & 255], 1);
    esrc[pos] = (int)(p & 0xffffu);
  }
}

// ---------------- GEMM + attention-score epilogue ----------------
// h16[n][128] (fp16, row-major) = in[n][0:K] @ W[K][128]; asrc/adst fp32 [n][2].
template<int K>
__global__ __launch_bounds__(256) void gemm_att_kernel(
    const float* __restrict__ in, const float* __restrict__ W,
    const float* __restrict__ att_s, const float* __restrict__ att_d,
    __half2* __restrict__ h16, float* __restrict__ asrc, float* __restrict__ adst, int n)
{
  __shared__ __align__(16) float sW[64*128];   // 32 KB
  __shared__ __align__(16) float sX[32*K];     // <=16 KB
  int t = threadIdx.x;
  int row0 = blockIdx.x*32;
  {
    const float4* X4 = (const float4*)(in + (size_t)row0*K);
    float4* sX4 = (float4*)sX;
    const int nx = 32*K/4;
    if(row0 + 32 <= n){
      for(int i = t; i < nx; i += 256) sX4[i] = X4[i];
    } else {
      for(int i = t; i < nx; i += 256){
        int r = row0 + i/(K/4);
        sX4[i] = (r < n) ? X4[i] : make_float4(0.f,0.f,0.f,0.f);
      }
    }
  }
  int lane = t & 63, wave = t >> 6;
  int r0 = wave*8;
  float2 acc[8];
  #pragma unroll
  for(int r = 0; r < 8; r++) acc[r] = make_float2(0.f, 0.f);

  for(int kt = 0; kt < K; kt += 64){
    __syncthreads();
    {
      const float4* W4 = (const float4*)(W + kt*128);
      float4* sW4 = (float4*)sW;
      for(int i = t; i < 2048; i += 256) sW4[i] = W4[i];
    }
    __syncthreads();
    const float2* sW2 = (const float2*)sW;
    for(int k = 0; k < 64; k += 4){
      float2 w0 = sW2[(k+0)*64 + lane];
      float2 w1 = sW2[(k+1)*64 + lane];
      float2 w2 = sW2[(k+2)*64 + lane];
      float2 w3 = sW2[(k+3)*64 + lane];
      #pragma unroll
      for(int r = 0; r < 8; r++){
        float4 xv = *(const float4*)&sX[(r0+r)*K + kt + k];
        acc[r].x = fmaf(xv.x, w0.x, acc[r].x);
        acc[r].y = fmaf(xv.x, w0.y, acc[r].y);
        acc[r].x = fmaf(xv.y, w1.x, acc[r].x);
        acc[r].y = fmaf(xv.y, w1.y, acc[r].y);
        acc[r].x = fmaf(xv.z, w2.x, acc[r].x);
        acc[r].y = fmaf(xv.z, w2.y, acc[r].y);
        acc[r].x = fmaf(xv.w, w3.x, acc[r].x);
        acc[r].y = fmaf(xv.w, w3.y, acc[r].y);
      }
    }
  }
  float2 as = ((const float2*)att_s)[lane];
  float2 ad = ((const float2*)att_d)[lane];
  #pragma unroll
  for(int r = 0; r < 8; r++){
    int row = row0 + r0 + r;
    if(row >= n) break;                         // wave-uniform
    h16[(size_t)row*64 + lane] = __float22half2_rn(acc[r]);
    float ps = acc[r].x*as.x + acc[r].y*as.y;
    float pd = acc[r].x*ad.x + acc[r].y*ad.y;
    #pragma unroll
    for(int m = 1; m < 32; m <<= 1){ ps += __shfl_xor(ps, m); pd += __shfl_xor(pd, m); }
    if(lane == 0)      { asrc[2*row]   = ps; adst[2*row]   = pd; }
    else if(lane == 32){ asrc[2*row+1] = ps; adst[2*row+1] = pd; }
  }
}

// ---------------- softmax + aggregation: 4 nodes/wave, 16 lanes/node ----------------
template<int LAYER>
__global__ __launch_bounds__(256) void aggregate_kernel(
    const uint4* __restrict__ h16u4, const float2* __restrict__ asrc2, const float2* __restrict__ adst2,
    const int* __restrict__ rowptr, const int* __restrict__ esrc,
    const float* __restrict__ bias, const float* __restrict__ fcW, const float* __restrict__ fcb,
    float* __restrict__ out, int n)
{
  __shared__ float4 sE[16][CAP+1];    // +1 row pad
  int t = threadIdx.x;
  int p = t & 15;
  int slot = t >> 4;
  int node = blockIdx.x*16 + slot;
  bool valid = node < n;
  int nd = valid ? node : 0;
  int beg = rowptr[nd], end = rowptr[nd+1];
  if(!valid){ beg = 0; end = 0; }
  float2 adn = adst2[nd];

  float s0 = 0.f, s1 = 0.f;
  for(int i = beg + p; i < end; i += 16){
    int s = esrc[i];
    float2 av = asrc2[s];
    float e0 = av.x + adn.x; e0 = (e0 > 0.f) ? e0 : 0.2f*e0;
    float e1 = av.y + adn.y; e1 = (e1 > 0.f) ? e1 : 0.2f*e1;
    float w0 = __expf(e0), w1 = __expf(e1);
    s0 += w0; s1 += w1;
    int j = i - beg;
    if(j < CAP) sE[slot][j] = make_float4(w0, w1, __int_as_float(s), 0.f);
  }
  #pragma unroll
  for(int m = 1; m < 16; m <<= 1){ s0 += __shfl_xor(s0, m); s1 += __shfl_xor(s1, m); }
  float inv0 = 1.f/(s0 + 1e-16f), inv1 = 1.f/(s1 + 1e-16f);

  int deg = end - beg;
  int dcap = deg < CAP ? deg : CAP;
  for(int j = p; j < dcap; j += 16){
    float4 e = sE[slot][j];
    e.x *= inv0; e.y *= inv1;
    sE[slot][j] = e;
  }
  int maxd = dcap;
  maxd = max(maxd, __shfl_xor(maxd, 16));
  maxd = max(maxd, __shfl_xor(maxd, 32));

  bool head1 = p >= 8;
  float2 acc0 = make_float2(0.f,0.f), acc1 = acc0, acc2 = acc0, acc3 = acc0;

  #pragma unroll 4
  for(int j = 0; j < maxd; j++){
    float4 e = sE[slot][j];
    bool act = j < dcap;
    float alpha = act ? (head1 ? e.y : e.x) : 0.f;
    int s = act ? __float_as_int(e.z) : 0;
    uint4 hv = h16u4[(size_t)s*16 + p];
    const __half2 h0 = *(const __half2*)&hv.x;
    const __half2 h1 = *(const __half2*)&hv.y;
    const __half2 h2 = *(const __half2*)&hv.z;
    const __half2 h3 = *(const __half2*)&hv.w;
    acc0.x = fmaf(__half2float(h0.x), alpha, acc0.x);
    acc0.y = fmaf(__half2float(h0.y), alpha, acc0.y);
    acc1.x = fmaf(__half2float(h1.x), alpha, acc1.x);
    acc1.y = fmaf(__half2float(h1.y), alpha, acc1.y);
    acc2.x = fmaf(__half2float(h2.x), alpha, acc2.x);
    acc2.y = fmaf(__half2float(h2.y), alpha, acc2.y);
    acc3.x = fmaf(__half2float(h3.x), alpha, acc3.x);
    acc3.y = fmaf(__half2float(h3.y), alpha, acc3.y);
  }
  float inv_mine = head1 ? inv1 : inv0;
  float adh = head1 ? adn.y : adn.x;
  for(int i2 = beg + CAP; i2 < end; i2++){
    int s = esrc[i2];
    float2 av = asrc2[s];
    float e_ = (head1 ? av.y : av.x) + adh;
    e_ = (e_ > 0.f) ? e_ : 0.2f*e_;
    float alpha = __expf(e_) * inv_mine;
    uint4 hv = h16u4[(size_t)s*16 + p];
    const __half2 h0 = *(const __half2*)&hv.x;
    const __half2 h1 = *(const __half2*)&hv.y;
    const __half2 h2 = *(const __half2*)&hv.z;
    const __half2 h3 = *(const __half2*)&hv.w;
    acc0.x = fmaf(__half2float(h0.x), alpha, acc0.x);
    acc0.y = fmaf(__half2float(h0.y), alpha, acc0.y);
    acc1.x = fmaf(__half2float(h1.x), alpha, acc1.x);
    acc1.y = fmaf(__half2float(h1.y), alpha, acc1.y);
    acc2.x = fmaf(__half2float(h2.x), alpha, acc2.x);
    acc2.y = fmaf(__half2float(h2.y), alpha, acc2.y);
    acc3.x = fmaf(__half2float(h3.x), alpha, acc3.x);
    acc3.y = fmaf(__half2float(h3.y), alpha, acc3.y);
  }

  float o0 = acc0.x + __shfl_xor(acc0.x, 8);
  float o1 = acc0.y + __shfl_xor(acc0.y, 8);
  float o2 = acc1.x + __shfl_xor(acc1.x, 8);
  float o3 = acc1.y + __shfl_xor(acc1.y, 8);
  float o4 = acc2.x + __shfl_xor(acc2.x, 8);
  float o5 = acc2.y + __shfl_xor(acc2.y, 8);
  float o6 = acc3.x + __shfl_xor(acc3.x, 8);
  float o7 = acc3.y + __shfl_xor(acc3.y, 8);

  if(LAYER == 1){
    if(!head1 && valid){
      float4 b0 = ((const float4*)bias)[2*p];
      float4 b1 = ((const float4*)bias)[2*p+1];
      float4 r0 = make_float4(fmaxf(fmaf(0.5f,o0,b0.x),0.f), fmaxf(fmaf(0.5f,o1,b0.y),0.f),
                              fmaxf(fmaf(0.5f,o2,b0.z),0.f), fmaxf(fmaf(0.5f,o3,b0.w),0.f));
      float4 r1 = make_float4(fmaxf(fmaf(0.5f,o4,b1.x),0.f), fmaxf(fmaf(0.5f,o5,b1.y),0.f),
                              fmaxf(fmaf(0.5f,o6,b1.z),0.f), fmaxf(fmaf(0.5f,o7,b1.w),0.f));
      float4* orow = (float4*)(out + (size_t)node*64 + 8*p);
      orow[0] = r0; orow[1] = r1;
    }
  } else {
    float partial = 0.f;
    if(!head1){
      float4 b0 = ((const float4*)bias)[2*p];
      float4 b1 = ((const float4*)bias)[2*p+1];
      float4 w0 = ((const float4*)fcW)[2*p];
      float4 w1 = ((const float4*)fcW)[2*p+1];
      partial  = fmaxf(fmaf(0.5f,o0,b0.x),0.f)*w0.x + fmaxf(fmaf(0.5f,o1,b0.y),0.f)*w0.y
               + fmaxf(fmaf(0.5f,o2,b0.z),0.f)*w0.z + fmaxf(fmaf(0.5f,o3,b0.w),0.f)*w0.w
               + fmaxf(fmaf(0.5f,o4,b1.x),0.f)*w1.x + fmaxf(fmaf(0.5f,o5,b1.y),0.f)*w1.y
               + fmaxf(fmaf(0.5f,o6,b1.z),0.f)*w1.z + fmaxf(fmaf(0.5f,o7,b1.w),0.f)*w1.w;
    }
    partial += __shfl_xor(partial, 1);
    partial += __shfl_xor(partial, 2);
    partial += __shfl_xor(partial, 4);
    if(p == 0 && valid) out[node] = partial + fcb[0];
  }
}

// ---------------- launch ----------------
extern "C" void kernel_launch(void* const* d_in, const int* in_sizes, int n_in,
                              void* d_out, int out_size, void* d_ws, size_t ws_size,
                              hipStream_t stream)
{
  const float* x   = (const float*)d_in[0];
  const int*   ei  = (const int*)  d_in[1];
  const float* W1  = (const float*)d_in[2];
  const float* as1 = (const float*)d_in[3];
  const float* ad1 = (const float*)d_in[4];
  const float* b1  = (const float*)d_in[5];
  const float* W2  = (const float*)d_in[6];
  const float* as2 = (const float*)d_in[7];
  const float* ad2 = (const float*)d_in[8];
  const float* b2  = (const float*)d_in[9];
  const float* fcW = (const float*)d_in[10];
  const float* fcb = (const float*)d_in[11];
  float* out = (float*)d_out;

  char* ws = (char*)d_ws;
  size_t off = 0;
  auto alloc = [&](size_t bytes) -> void* {
    void* p = ws + off;
    off += (bytes + 255) & ~(size_t)255;
    return p;
  };
  int*          rowptr      = (int*)         alloc((NNODES+1)*sizeof(int));
  int*          bucketHist  = (int*)         alloc(NB*sizeof(int));
  int*          bucketBase  = (int*)         alloc((NB+1)*sizeof(int));
  int*          bucketCursor= (int*)         alloc(NB*sizeof(int));
  unsigned int* edgebuf     = (unsigned int*)alloc((size_t)EP*sizeof(unsigned int));
  int*          esrc        = (int*)         alloc((size_t)EP*sizeof(int));
  __half2*      h16         = (__half2*)     alloc((size_t)NNODES*64*sizeof(__half2));
  float*        asrc        = (float*)       alloc((size_t)NNODES*2*sizeof(float));
  float*        adst        = (float*)       alloc((size_t)NNODES*2*sizeof(float));
  float*        out1        = (float*)       alloc((size_t)NNODES*64*sizeof(float));

  const int nchunks = (EP + CHUNK - 1)/CHUNK;   // 104

  hipMemsetAsync(bucketHist, 0, NB*sizeof(int), stream);
  hipLaunchKernelGGL(bucket_hist_kernel, dim3(nchunks), dim3(256), 0, stream, ei, bucketHist);
  hipLaunchKernelGGL(bucket_scan_kernel, dim3(1),       dim3(256), 0, stream, bucketHist, bucketBase, bucketCursor, rowptr);
  hipLaunchKernelGGL(partition_kernel,   dim3(nchunks), dim3(256), 0, stream, ei, bucketCursor, edgebuf);
  hipLaunchKernelGGL(bucket_sort_kernel, dim3(NB),      dim3(256), 0, stream, edgebuf, bucketBase, rowptr, esrc);

  hipLaunchKernelGGL((gemm_att_kernel<128>), dim3((NNODES+31)/32), dim3(256), 0, stream,
                     x, W1, as1, ad1, h16, asrc, adst, NNODES);
  hipLaunchKernelGGL((aggregate_kernel<1>),  dim3((NNODES+15)/16), dim3(256), 0, stream,
                     (const uint4*)h16, (const float2*)asrc, (const float2*)adst, rowptr, esrc,
                     b1, (const float*)nullptr, (const float*)nullptr, out1, NNODES);
  hipLaunchKernelGGL((gemm_att_kernel<64>),  dim3((NNODES+31)/32), dim3(256), 0, stream,
                     out1, W2, as2, ad2, h16, asrc, adst, NNODES);
  hipLaunchKernelGGL((aggregate_kernel<2>),  dim3((NNODES+15)/16), dim3(256), 0, stream,
                     (const uint4*)h16, (const float2*)asrc, (const float2*)adst, rowptr, esrc,
                     b2, fcW, fcb, out, NNODES);
}

// Round 5
// 249.676 us; speedup vs baseline: 1.5601x; 1.0489x over previous
//
#include <hip/hip_runtime.h>
#include <hip/hip_fp16.h>

#define NNODES 50000
#define NEDGES 800000
#define EP (NEDGES + NNODES)   // 850000 edges incl. self-loops
#define CAP 64                 // per-node LDS edge cache in aggregate
#define NB 196                 // dst buckets of 256 nodes: ceil(50000/256)
#define CHUNK 8192             // edges per partition block

// ---------------- CSR build: two-level counting sort ----------------
__global__ __launch_bounds__(256) void bucket_hist_kernel(const int* __restrict__ ei, int* __restrict__ bucketHist){
  __shared__ int lh[NB];
  int t = threadIdx.x;
  for(int i = t; i < NB; i += 256) lh[i] = 0;
  __syncthreads();
  int base = blockIdx.x*CHUNK;
  #pragma unroll
  for(int k = 0; k < CHUNK; k += 256){
    int e = base + k + t;
    if(e < EP){
      int d = (e < NEDGES) ? ei[NEDGES + e] : (e - NEDGES);
      atomicAdd(&lh[d >> 8], 1);
    }
  }
  __syncthreads();
  for(int i = t; i < NB; i += 256) if(lh[i]) atomicAdd(&bucketHist[i], lh[i]);
}

__global__ __launch_bounds__(256) void bucket_scan_kernel(const int* __restrict__ bucketHist,
                                                          int* __restrict__ bucketBase,
                                                          int* __restrict__ bucketCursor,
                                                          int* __restrict__ rowptr){
  __shared__ int sb[256];
  int t = threadIdx.x;
  int v = (t < NB) ? bucketHist[t] : 0;
  sb[t] = v; __syncthreads();
  int acc = v;
  #pragma unroll
  for(int d = 1; d < 256; d <<= 1){
    int o = (t >= d) ? sb[t-d] : 0;
    __syncthreads();
    acc += o; sb[t] = acc;
    __syncthreads();
  }
  int excl = acc - v;
  if(t <= NB) bucketBase[t] = excl;
  if(t <  NB) bucketCursor[t] = excl;
  if(t == 0)  rowptr[NNODES] = EP;
}

__global__ __launch_bounds__(256) void partition_kernel(const int* __restrict__ ei,
                                                        int* __restrict__ bucketCursor,
                                                        unsigned int* __restrict__ edgebuf){
  __shared__ unsigned int stage[CHUNK];      // 32 KB
  __shared__ int lh[NB], lbase[NB], lcur[NB], gbase[NB];
  __shared__ int sb[256];
  int t = threadIdx.x;
  for(int i = t; i < NB; i += 256) lh[i] = 0;
  __syncthreads();
  int base = blockIdx.x*CHUNK;
  unsigned int pk[CHUNK/256];
  #pragma unroll
  for(int k = 0; k < CHUNK/256; k++){
    int e = base + k*256 + t;
    unsigned int p = 0xffffffffu;
    if(e < EP){
      int s, d;
      if(e < NEDGES){ s = ei[e]; d = ei[NEDGES + e]; }
      else          { s = d = e - NEDGES; }
      p = ((unsigned int)d << 16) | (unsigned int)s;
      atomicAdd(&lh[d >> 8], 1);
    }
    pk[k] = p;
  }
  __syncthreads();
  int v = (t < NB) ? lh[t] : 0;
  sb[t] = v; __syncthreads();
  int acc = v;
  #pragma unroll
  for(int d = 1; d < 256; d <<= 1){
    int o = (t >= d) ? sb[t-d] : 0;
    __syncthreads();
    acc += o; sb[t] = acc;
    __syncthreads();
  }
  int excl = acc - v;
  if(t < NB){
    lbase[t] = excl; lcur[t] = excl;
    gbase[t] = v ? atomicAdd(&bucketCursor[t], v) : 0;
  }
  __syncthreads();
  #pragma unroll
  for(int k = 0; k < CHUNK/256; k++){
    unsigned int p = pk[k];
    if(p != 0xffffffffu){
      int bin = p >> 24;
      int r = atomicAdd(&lcur[bin], 1);
      stage[r] = p;
    }
  }
  __syncthreads();
  int nvalid = EP - base; if(nvalid > CHUNK) nvalid = CHUNK;
  for(int j = t; j < nvalid; j += 256){
    unsigned int p = stage[j];
    int bin = p >> 24;
    edgebuf[gbase[bin] + (j - lbase[bin])] = p;
  }
}

__global__ __launch_bounds__(256) void bucket_sort_kernel(const unsigned int* __restrict__ edgebuf,
                                                          const int* __restrict__ bucketBase,
                                                          int* __restrict__ rowptr,
                                                          int* __restrict__ esrc){
  __shared__ int lh[256], lcur[256], sb[256];
  int b = blockIdx.x, t = threadIdx.x;
  int lo = bucketBase[b], hi = bucketBase[b+1];
  lh[t] = 0;
  __syncthreads();
  for(int i = lo + t; i < hi; i += 256)
    atomicAdd(&lh[(edgebuf[i] >> 16) & 255], 1);
  __syncthreads();
  int v = lh[t];
  sb[t] = v; __syncthreads();
  int acc = v;
  #pragma unroll
  for(int d = 1; d < 256; d <<= 1){
    int o = (t >= d) ? sb[t-d] : 0;
    __syncthreads();
    acc += o; sb[t] = acc;
    __syncthreads();
  }
  int excl = acc - v;
  lcur[t] = lo + excl;
  int node = b*256 + t;
  if(node < NNODES) rowptr[node] = lo + excl;
  __syncthreads();
  for(int i = lo + t; i < hi; i += 256){
    unsigned int p = edgebuf[i];
    int pos = atomicAdd(&lcur[(p >> 16) & 255], 1);
    esrc[pos] = (int)(p & 0xffffu);
  }
}

// ---------------- GEMM + attention-score epilogue ----------------
// Block: 64 rows x 128 cols, K-tiles of 32. Lane tile: 8 rows x 4 cols (32 acc).
// sW 16KB + sX 8KB = 24KB LDS; VALU-bound inner loop (128 FMA : 12 ds_read_b128).
// h16[n][128] (fp16) = in @ W; asrc/adst fp32 [n][2] via per-head lane reduction.
template<int K>
__global__ __launch_bounds__(256, 4) void gemm_att_kernel(
    const float* __restrict__ in, const float* __restrict__ W,
    const float* __restrict__ att_s, const float* __restrict__ att_d,
    __half2* __restrict__ h16, float* __restrict__ asrc, float* __restrict__ adst, int n)
{
  __shared__ __align__(16) float sW[32*128];   // 16 KB
  __shared__ __align__(16) float sX[64*32];    // 8 KB
  int t = threadIdx.x;
  int row0 = blockIdx.x*64;
  int lane = t & 63;
  int c  = lane & 31;          // col-quad: cols 4c..4c+3 (c<16 head0, c>=16 head1)
  int rg = lane >> 5;          // row subgroup within wave
  int wave = t >> 6;
  int rbase = wave*16 + rg*8;  // wave covers 16 rows

  float4 acc[8];
  #pragma unroll
  for(int r = 0; r < 8; r++) acc[r] = make_float4(0.f,0.f,0.f,0.f);

  for(int kt = 0; kt < K; kt += 32){
    // stage W[kt..kt+32][0..128] (4096 floats, coalesced)
    {
      const float4* W4 = (const float4*)(W + (size_t)kt*128);
      float4* sW4 = (float4*)sW;
      #pragma unroll
      for(int i = 0; i < 4; i++) sW4[t + i*256] = W4[t + i*256];
    }
    // stage X rows row0..row0+64, k kt..kt+32 (512 float4)
    {
      float4* sX4 = (float4*)sX;
      #pragma unroll
      for(int i = 0; i < 2; i++){
        int idx = t + i*256;
        int r = idx >> 3, j = idx & 7;
        int grow = row0 + r;
        float4 v = make_float4(0.f,0.f,0.f,0.f);
        if(grow < n) v = ((const float4*)(in + (size_t)grow*K + kt))[j];
        sX4[idx] = v;
      }
    }
    __syncthreads();
    const float4* sW4 = (const float4*)sW;
    const float4* sX4 = (const float4*)sX;
    #pragma unroll
    for(int kq = 0; kq < 8; kq++){
      float4 w0 = sW4[(kq*4+0)*32 + c];
      float4 w1 = sW4[(kq*4+1)*32 + c];
      float4 w2 = sW4[(kq*4+2)*32 + c];
      float4 w3 = sW4[(kq*4+3)*32 + c];
      #pragma unroll
      for(int r = 0; r < 8; r++){
        float4 xv = sX4[(rbase + r)*8 + kq];   // 32-lane broadcast
        acc[r].x = fmaf(xv.x, w0.x, acc[r].x);
        acc[r].y = fmaf(xv.x, w0.y, acc[r].y);
        acc[r].z = fmaf(xv.x, w0.z, acc[r].z);
        acc[r].w = fmaf(xv.x, w0.w, acc[r].w);
        acc[r].x = fmaf(xv.y, w1.x, acc[r].x);
        acc[r].y = fmaf(xv.y, w1.y, acc[r].y);
        acc[r].z = fmaf(xv.y, w1.z, acc[r].z);
        acc[r].w = fmaf(xv.y, w1.w, acc[r].w);
        acc[r].x = fmaf(xv.z, w2.x, acc[r].x);
        acc[r].y = fmaf(xv.z, w2.y, acc[r].y);
        acc[r].z = fmaf(xv.z, w2.z, acc[r].z);
        acc[r].w = fmaf(xv.z, w2.w, acc[r].w);
        acc[r].x = fmaf(xv.w, w3.x, acc[r].x);
        acc[r].y = fmaf(xv.w, w3.y, acc[r].y);
        acc[r].z = fmaf(xv.w, w3.z, acc[r].z);
        acc[r].w = fmaf(xv.w, w3.w, acc[r].w);
      }
    }
    __syncthreads();
  }

  float4 as4 = ((const float4*)att_s)[c];
  float4 ad4 = ((const float4*)att_d)[c];
  #pragma unroll
  for(int r = 0; r < 8; r++){
    int row = row0 + rbase + r;
    bool ok = row < n;
    if(ok){
      __half2 p0 = __float22half2_rn(make_float2(acc[r].x, acc[r].y));
      __half2 p1 = __float22half2_rn(make_float2(acc[r].z, acc[r].w));
      uint2 pk;
      pk.x = *(unsigned int*)&p0;
      pk.y = *(unsigned int*)&p1;
      ((uint2*)h16)[(size_t)row*32 + c] = pk;
    }
    float ps = acc[r].x*as4.x + acc[r].y*as4.y + acc[r].z*as4.z + acc[r].w*as4.w;
    float pd = acc[r].x*ad4.x + acc[r].y*ad4.y + acc[r].z*ad4.z + acc[r].w*ad4.w;
    #pragma unroll
    for(int m = 1; m < 16; m <<= 1){ ps += __shfl_xor(ps, m); pd += __shfl_xor(pd, m); }
    if(ok && (c & 15) == 0){
      int head = c >> 4;
      asrc[2*row + head] = ps;
      adst[2*row + head] = pd;
    }
  }
}

// ---------------- softmax + aggregation: 4 nodes/wave, 16 lanes/node ----------------
template<int LAYER>
__global__ __launch_bounds__(256) void aggregate_kernel(
    const uint4* __restrict__ h16u4, const float2* __restrict__ asrc2, const float2* __restrict__ adst2,
    const int* __restrict__ rowptr, const int* __restrict__ esrc,
    const float* __restrict__ bias, const float* __restrict__ fcW, const float* __restrict__ fcb,
    float* __restrict__ out, int n)
{
  __shared__ float4 sE[16][CAP+1];
  int t = threadIdx.x;
  int p = t & 15;
  int slot = t >> 4;
  int node = blockIdx.x*16 + slot;
  bool valid = node < n;
  int nd = valid ? node : 0;
  int beg = rowptr[nd], end = rowptr[nd+1];
  if(!valid){ beg = 0; end = 0; }
  float2 adn = adst2[nd];

  float s0 = 0.f, s1 = 0.f;
  for(int i = beg + p; i < end; i += 16){
    int s = esrc[i];
    float2 av = asrc2[s];
    float e0 = av.x + adn.x; e0 = (e0 > 0.f) ? e0 : 0.2f*e0;
    float e1 = av.y + adn.y; e1 = (e1 > 0.f) ? e1 : 0.2f*e1;
    float w0 = __expf(e0), w1 = __expf(e1);
    s0 += w0; s1 += w1;
    int j = i - beg;
    if(j < CAP) sE[slot][j] = make_float4(w0, w1, __int_as_float(s), 0.f);
  }
  #pragma unroll
  for(int m = 1; m < 16; m <<= 1){ s0 += __shfl_xor(s0, m); s1 += __shfl_xor(s1, m); }
  float inv0 = 1.f/(s0 + 1e-16f), inv1 = 1.f/(s1 + 1e-16f);

  int deg = end - beg;
  int dcap = deg < CAP ? deg : CAP;
  for(int j = p; j < dcap; j += 16){
    float4 e = sE[slot][j];
    e.x *= inv0; e.y *= inv1;
    sE[slot][j] = e;
  }
  int maxd = dcap;
  maxd = max(maxd, __shfl_xor(maxd, 16));
  maxd = max(maxd, __shfl_xor(maxd, 32));

  bool head1 = p >= 8;
  float2 acc0 = make_float2(0.f,0.f), acc1 = acc0, acc2 = acc0, acc3 = acc0;

  #pragma unroll 4
  for(int j = 0; j < maxd; j++){
    float4 e = sE[slot][j];
    bool act = j < dcap;
    float alpha = act ? (head1 ? e.y : e.x) : 0.f;
    int s = act ? __float_as_int(e.z) : 0;
    uint4 hv = h16u4[(size_t)s*16 + p];
    const __half2 h0 = *(const __half2*)&hv.x;
    const __half2 h1 = *(const __half2*)&hv.y;
    const __half2 h2 = *(const __half2*)&hv.z;
    const __half2 h3 = *(const __half2*)&hv.w;
    acc0.x = fmaf(__half2float(h0.x), alpha, acc0.x);
    acc0.y = fmaf(__half2float(h0.y), alpha, acc0.y);
    acc1.x = fmaf(__half2float(h1.x), alpha, acc1.x);
    acc1.y = fmaf(__half2float(h1.y), alpha, acc1.y);
    acc2.x = fmaf(__half2float(h2.x), alpha, acc2.x);
    acc2.y = fmaf(__half2float(h2.y), alpha, acc2.y);
    acc3.x = fmaf(__half2float(h3.x), alpha, acc3.x);
    acc3.y = fmaf(__half2float(h3.y), alpha, acc3.y);
  }
  float inv_mine = head1 ? inv1 : inv0;
  float adh = head1 ? adn.y : adn.x;
  for(int i2 = beg + CAP; i2 < end; i2++){
    int s = esrc[i2];
    float2 av = asrc2[s];
    float e_ = (head1 ? av.y : av.x) + adh;
    e_ = (e_ > 0.f) ? e_ : 0.2f*e_;
    float alpha = __expf(e_) * inv_mine;
    uint4 hv = h16u4[(size_t)s*16 + p];
    const __half2 h0 = *(const __half2*)&hv.x;
    const __half2 h1 = *(const __half2*)&hv.y;
    const __half2 h2 = *(const __half2*)&hv.z;
    const __half2 h3 = *(const __half2*)&hv.w;
    acc0.x = fmaf(__half2float(h0.x), alpha, acc0.x);
    acc0.y = fmaf(__half2float(h0.y), alpha, acc0.y);
    acc1.x = fmaf(__half2float(h1.x), alpha, acc1.x);
    acc1.y = fmaf(__half2float(h1.y), alpha, acc1.y);
    acc2.x = fmaf(__half2float(h2.x), alpha, acc2.x);
    acc2.y = fmaf(__half2float(h2.y), alpha, acc2.y);
    acc3.x = fmaf(__half2float(h3.x), alpha, acc3.x);
    acc3.y = fmaf(__half2float(h3.y), alpha, acc3.y);
  }

  float o0 = acc0.x + __shfl_xor(acc0.x, 8);
  float o1 = acc0.y + __shfl_xor(acc0.y, 8);
  float o2 = acc1.x + __shfl_xor(acc1.x, 8);
  float o3 = acc1.y + __shfl_xor(acc1.y, 8);
  float o4 = acc2.x + __shfl_xor(acc2.x, 8);
  float o5 = acc2.y + __shfl_xor(acc2.y, 8);
  float o6 = acc3.x + __shfl_xor(acc3.x, 8);
  float o7 = acc3.y + __shfl_xor(acc3.y, 8);

  if(LAYER == 1){
    if(!head1 && valid){
      float4 b0 = ((const float4*)bias)[2*p];
      float4 b1 = ((const float4*)bias)[2*p+1];
      float4 r0 = make_float4(fmaxf(fmaf(0.5f,o0,b0.x),0.f), fmaxf(fmaf(0.5f,o1,b0.y),0.f),
                              fmaxf(fmaf(0.5f,o2,b0.z),0.f), fmaxf(fmaf(0.5f,o3,b0.w),0.f));
      float4 r1 = make_float4(fmaxf(fmaf(0.5f,o4,b1.x),0.f), fmaxf(fmaf(0.5f,o5,b1.y),0.f),
                              fmaxf(fmaf(0.5f,o6,b1.z),0.f), fmaxf(fmaf(0.5f,o7,b1.w),0.f));
      float4* orow = (float4*)(out + (size_t)node*64 + 8*p);
      orow[0] = r0; orow[1] = r1;
    }
  } else {
    float partial = 0.f;
    if(!head1){
      float4 b0 = ((const float4*)bias)[2*p];
      float4 b1 = ((const float4*)bias)[2*p+1];
      float4 w0 = ((const float4*)fcW)[2*p];
      float4 w1 = ((const float4*)fcW)[2*p+1];
      partial  = fmaxf(fmaf(0.5f,o0,b0.x),0.f)*w0.x + fmaxf(fmaf(0.5f,o1,b0.y),0.f)*w0.y
               + fmaxf(fmaf(0.5f,o2,b0.z),0.f)*w0.z + fmaxf(fmaf(0.5f,o3,b0.w),0.f)*w0.w
               + fmaxf(fmaf(0.5f,o4,b1.x),0.f)*w1.x + fmaxf(fmaf(0.5f,o5,b1.y),0.f)*w1.y
               + fmaxf(fmaf(0.5f,o6,b1.z),0.f)*w1.z + fmaxf(fmaf(0.5f,o7,b1.w),0.f)*w1.w;
    }
    partial += __shfl_xor(partial, 1);
    partial += __shfl_xor(partial, 2);
    partial += __shfl_xor(partial, 4);
    if(p == 0 && valid) out[node] = partial + fcb[0];
  }
}

// ---------------- launch ----------------
extern "C" void kernel_launch(void* const* d_in, const int* in_sizes, int n_in,
                              void* d_out, int out_size, void* d_ws, size_t ws_size,
                              hipStream_t stream)
{
  const float* x   = (const float*)d_in[0];
  const int*   ei  = (const int*)  d_in[1];
  const float* W1  = (const float*)d_in[2];
  const float* as1 = (const float*)d_in[3];
  const float* ad1 = (const float*)d_in[4];
  const float* b1  = (const float*)d_in[5];
  const float* W2  = (const float*)d_in[6];
  const float* as2 = (const float*)d_in[7];
  const float* ad2 = (const float*)d_in[8];
  const float* b2  = (const float*)d_in[9];
  const float* fcW = (const float*)d_in[10];
  const float* fcb = (const float*)d_in[11];
  float* out = (float*)d_out;

  char* ws = (char*)d_ws;
  size_t off = 0;
  auto alloc = [&](size_t bytes) -> void* {
    void* p = ws + off;
    off += (bytes + 255) & ~(size_t)255;
    return p;
  };
  int*          rowptr      = (int*)         alloc((NNODES+1)*sizeof(int));
  int*          bucketHist  = (int*)         alloc(NB*sizeof(int));
  int*          bucketBase  = (int*)         alloc((NB+1)*sizeof(int));
  int*          bucketCursor= (int*)         alloc(NB*sizeof(int));
  unsigned int* edgebuf     = (unsigned int*)alloc((size_t)EP*sizeof(unsigned int));
  int*          esrc        = (int*)         alloc((size_t)EP*sizeof(int));
  __half2*      h16         = (__half2*)     alloc((size_t)NNODES*64*sizeof(__half2));
  float*        asrc        = (float*)       alloc((size_t)NNODES*2*sizeof(float));
  float*        adst        = (float*)       alloc((size_t)NNODES*2*sizeof(float));
  float*        out1        = (float*)       alloc((size_t)NNODES*64*sizeof(float));

  const int nchunks = (EP + CHUNK - 1)/CHUNK;   // 104

  hipMemsetAsync(bucketHist, 0, NB*sizeof(int), stream);
  hipLaunchKernelGGL(bucket_hist_kernel, dim3(nchunks), dim3(256), 0, stream, ei, bucketHist);
  hipLaunchKernelGGL(bucket_scan_kernel, dim3(1),       dim3(256), 0, stream, bucketHist, bucketBase, bucketCursor, rowptr);
  hipLaunchKernelGGL(partition_kernel,   dim3(nchunks), dim3(256), 0, stream, ei, bucketCursor, edgebuf);
  hipLaunchKernelGGL(bucket_sort_kernel, dim3(NB),      dim3(256), 0, stream, edgebuf, bucketBase, rowptr, esrc);

  hipLaunchKernelGGL((gemm_att_kernel<128>), dim3((NNODES+63)/64), dim3(256), 0, stream,
                     x, W1, as1, ad1, h16, asrc, adst, NNODES);
  hipLaunchKernelGGL((aggregate_kernel<1>),  dim3((NNODES+15)/16), dim3(256), 0, stream,
                     (const uint4*)h16, (const float2*)asrc, (const float2*)adst, rowptr, esrc,
                     b1, (const float*)nullptr, (const float*)nullptr, out1, NNODES);
  hipLaunchKernelGGL((gemm_att_kernel<64>),  dim3((NNODES+63)/64), dim3(256), 0, stream,
                     out1, W2, as2, ad2, h16, asrc, adst, NNODES);
  hipLaunchKernelGGL((aggregate_kernel<2>),  dim3((NNODES+15)/16), dim3(256), 0, stream,
                     (const uint4*)h16, (const float2*)asrc, (const float2*)adst, rowptr, esrc,
                     b2, fcW, fcb, out, NNODES);
}